// Round 14
// baseline (149.201 us; speedup 1.0000x reference)
//
#include <hip/hip_runtime.h>
#include <hip/hip_bf16.h>

#define S_LEN 2048
#define EMB   512
#define NH    8
#define DH    64
#define NB    4

typedef float f32x4  __attribute__((ext_vector_type(4)));
typedef short short8 __attribute__((ext_vector_type(8)));
typedef short short4v __attribute__((ext_vector_type(4)));

__device__ __forceinline__ unsigned short f2bf_rn(float f) {
    return __builtin_bit_cast(unsigned short, __float2bfloat16(f));
}

__device__ __forceinline__ f32x4 mfma16(short8 a, short8 b, f32x4 c) {
    return __builtin_amdgcn_mfma_f32_16x16x32_bf16(a, b, c, 0, 0, 0);
}

// read one MFMA A/B fragment octet (8 bf16) from a swizzled 64x64 tile
__device__ __forceinline__ short8 frag_read(const unsigned short* lds, int row, int oct)
{
    const char* src = (const char*)lds + row * 128 + ((oct * 16) ^ ((row & 7) << 4));
    return *reinterpret_cast<const short8*>(src);
}

// inverse of the vT column permutation pi:
// pi(p) = (p&32) + ((p>>3)&3)*4 + (p&3) + ((p&4)?16:0)
// Note: pinv(k)&3 == k&3, so 4-aligned source quads map to 4-aligned stored quads
// in order: pinv(4a+c) = pinv(4a)+c for c<4.
__device__ __forceinline__ int pinv(int k) {
    return (k & 32) + ((k >> 2) & 3) * 8 + (k & 3) + ((k & 16) >> 2);
}

// stage a 64x64 bf16 tile into LDS with XOR swizzle (256 threads)
__device__ __forceinline__ void stage_tile_bf16(const unsigned short* __restrict__ g,
                                                int gstride, unsigned short* lds, int tid)
{
    #pragma unroll
    for (int c = tid; c < 512; c += 256) {
        const int r = c >> 3, s = c & 7;
        short8 v = *reinterpret_cast<const short8*>(g + (size_t)r * gstride + s * 8);
        char* dst = (char*)lds + r * 128 + ((s * 16) ^ ((r & 7) << 4));
        *reinterpret_cast<short8*>(dst) = v;
    }
}

// softmax 16 scores -> bf16 A-fragments + running denom partial (4-way tree sum)
__device__ __forceinline__ void softmax_pack(const f32x4 C[4], bool diag, int ws, int og,
                                             int rowg, float& dsum, short8& pa0, short8& pa1)
{
    constexpr float SM_SCALE = 0.04419417382415922f; // 1/sqrt(512)
    float rs[4];
    unsigned short pw[16];
    if (!diag) {
        #pragma unroll
        for (int t = 0; t < 4; ++t) {
            float a = 0.f;
            #pragma unroll
            for (int r = 0; r < 4; ++r) {
                const float wv = __expf(C[t][r] * SM_SCALE);
                a += wv;
                pw[t * 4 + r] = f2bf_rn(wv);
            }
            rs[t] = a;
        }
    } else {
        #pragma unroll
        for (int t = 0; t < 4; ++t) {
            float a = 0.f;
            #pragma unroll
            for (int r = 0; r < 4; ++r) {
                const bool keep = (t > ws) || (t == ws && (og * 4 + r) > rowg);
                const float wv = keep ? __expf(C[t][r] * SM_SCALE) : 0.f;
                a += wv;
                pw[t * 4 + r] = f2bf_rn(wv);
            }
            rs[t] = a;
        }
    }
    dsum += (rs[0] + rs[1]) + (rs[2] + rs[3]);
    #pragma unroll
    for (int i = 0; i < 8; ++i) { pa0[i] = (short)pw[i]; pa1[i] = (short)pw[8 + i]; }
}

// ---------------- Kernel 0: one-time weight+E f32->bf16 conversion ----------------
__global__ __launch_bounds__(256) void prep_we(
    const float* __restrict__ Wq, const float* __restrict__ Wk,
    const float* __restrict__ Wv, const float* __restrict__ Wo,
    const float* __restrict__ E,
    unsigned short* __restrict__ wq, unsigned short* __restrict__ wk,
    unsigned short* __restrict__ wv, unsigned short* __restrict__ wo,
    unsigned short* __restrict__ eb)
{
    const int i = blockIdx.x * 256 + threadIdx.x;
    if (i < 4096) {
        wq[i] = f2bf_rn(Wq[i]);
        wk[i] = f2bf_rn(Wk[i]);
        wv[i] = f2bf_rn(Wv[i]);
    }
    if (i < EMB * EMB) wo[i] = f2bf_rn(Wo[i]);
    if (i < S_LEN * DH) {
        const int dlt = i >> 6, d = i & 63;
        eb[i] = f2bf_rn(E[(size_t)(S_LEN - 1 - dlt) * DH + d]);
    }
}

// ------- Kernel 1: q/k/v projections via MFMA; V written TRANSPOSED (pi-permuted) -------
__global__ __launch_bounds__(256) void qkv_mfma(
    const float* __restrict__ x,
    const unsigned short* __restrict__ Wqb, const float* __restrict__ bq,
    const unsigned short* __restrict__ Wkb, const float* __restrict__ bk,
    const unsigned short* __restrict__ Wvb, const float* __restrict__ bv,
    unsigned short* __restrict__ qg, unsigned short* __restrict__ kg,
    unsigned short* __restrict__ vtg)
{
    __shared__ unsigned short w_lds[3][64 * 64];   // reused post-MFMA for V exchange

    const int tid  = threadIdx.x;
    const int lane = tid & 63;
    const int w    = tid >> 6;
    const int rowg = lane & 15;
    const int og   = lane >> 4;

    stage_tile_bf16(Wqb, 64, w_lds[0], tid);
    stage_tile_bf16(Wkb, 64, w_lds[1], tid);
    stage_tile_bf16(Wvb, 64, w_lds[2], tid);

    float bias[3][4];
    #pragma unroll
    for (int t = 0; t < 4; ++t) {
        bias[0][t] = bq[16 * t + rowg];
        bias[1][t] = bk[16 * t + rowg];
        bias[2][t] = bv[16 * t + rowg];
    }

    const int m0 = blockIdx.x * 64 + 16 * w;
    const float* xr = x + (size_t)(m0 + rowg) * 64;
    const float4 a0 = *(const float4*)(xr + og * 8);
    const float4 a1 = *(const float4*)(xr + og * 8 + 4);
    const float4 a2 = *(const float4*)(xr + 32 + og * 8);
    const float4 a3 = *(const float4*)(xr + 32 + og * 8 + 4);
    short8 af0, af1;
    af0[0] = (short)f2bf_rn(a0.x); af0[1] = (short)f2bf_rn(a0.y);
    af0[2] = (short)f2bf_rn(a0.z); af0[3] = (short)f2bf_rn(a0.w);
    af0[4] = (short)f2bf_rn(a1.x); af0[5] = (short)f2bf_rn(a1.y);
    af0[6] = (short)f2bf_rn(a1.z); af0[7] = (short)f2bf_rn(a1.w);
    af1[0] = (short)f2bf_rn(a2.x); af1[1] = (short)f2bf_rn(a2.y);
    af1[2] = (short)f2bf_rn(a2.z); af1[3] = (short)f2bf_rn(a2.w);
    af1[4] = (short)f2bf_rn(a3.x); af1[5] = (short)f2bf_rn(a3.y);
    af1[6] = (short)f2bf_rn(a3.z); af1[7] = (short)f2bf_rn(a3.w);

    __syncthreads();

    f32x4 acc[3][4];
    #pragma unroll
    for (int m = 0; m < 3; ++m)
        #pragma unroll
        for (int t = 0; t < 4; ++t) {
            const float b = bias[m][t];
            acc[m][t] = (f32x4){b, b, b, b};
        }

    #pragma unroll
    for (int m = 0; m < 3; ++m)
        #pragma unroll
        for (int t = 0; t < 4; ++t) {
            acc[m][t] = mfma16(af0, frag_read(w_lds[m], 16 * t + rowg, og),     acc[m][t]);
            acc[m][t] = mfma16(af1, frag_read(w_lds[m], 16 * t + rowg, og + 4), acc[m][t]);
        }

    // ---- write q, k (row-major bf16) ----
    unsigned short* outp[2] = {qg, kg};
    #pragma unroll
    for (int m = 0; m < 2; ++m)
        #pragma unroll
        for (int r = 0; r < 4; ++r) {
            const int mr = (blockIdx.x * 64 + 16 * w) + og * 4 + r;
            const int tk = mr >> 3, h = mr & 7;
            const int n = tk >> 11, s = tk & 2047;
            const size_t rowb = (((size_t)(n * NH + h)) * S_LEN + s) * 64;
            #pragma unroll
            for (int t = 0; t < 4; ++t)
                outp[m][rowb + 16 * t + rowg] = f2bf_rn(acc[m][t][r]);
        }

    // ---- V: LDS exchange -> transposed, pi-permuted write ----
    __syncthreads();                           // all waves done reading w_lds
    unsigned short* t_lds = w_lds[0];          // [64][72] exchange buffer
    #pragma unroll
    for (int t = 0; t < 4; ++t)
        #pragma unroll
        for (int r = 0; r < 4; ++r)
            t_lds[(16 * w + og * 4 + r) * 72 + 16 * t + rowg] = f2bf_rn(acc[2][t][r]);
    __syncthreads();

    const int tk0 = blockIdx.x * 8;            // 8 tokens per block, same n
    const int n   = tk0 >> 11;
    const int s0  = tk0 & 2047;
    const int gbase = s0 & ~63;                // 64-token pi-group base
    const int a8    = s0 & 63;                 // 8-aligned offset within group
    #pragma unroll
    for (int i = 0; i < 4; ++i) {
        const int c  = tid + 256 * i;          // 0..1023 chunk id
        const int qd = c & 1;                  // source quad within the 8 tokens
        const int d  = (c >> 1) & 63;
        const int h  = c >> 7;
        const int col = gbase + pinv(a8 + 4 * qd);
        short4v pk;
        #pragma unroll
        for (int cc = 0; cc < 4; ++cc)
            pk[cc] = (short)t_lds[((4 * qd + cc) * 8 + h) * 72 + d];
        unsigned short* dst = vtg + ((size_t)(n * NH + h) * DH + d) * S_LEN + col;
        *reinterpret_cast<short4v*>(dst) = pk;
    }
}

// ------- Kernel 2: fused MFMA attention (R9 phase A; phase B with E-in-registers) -------
// LDS overlay (40960 B total):
//   bytes [    0,16384): phase A K double-buffer  |  phase B p_lds double-buffer
//   bytes [16384,40960): phase A vT TRIPLE buffer
//   bytes [16384,32768): phase B vT double-buffer (slot 2 unused in phase B)
__global__ __launch_bounds__(256) void attn_mfma(
    const unsigned short* __restrict__ qg,
    const unsigned short* __restrict__ kg,
    const unsigned short* __restrict__ vtg,
    const unsigned short* __restrict__ eg,
    unsigned short* __restrict__ z)
{
    __shared__ __align__(16) unsigned short smem[20480];   // 40960 bytes

    constexpr float UNI = 1.0f / 2048.0f;

    const int nqt = S_LEN / 64;                   // 32
    const int bid = blockIdx.x;
    const int qt  = (nqt - 1) - (bid >> 5);       // heavy blocks first
    const int nh  = bid & 31;
    const int q0  = qt * 64;
    const size_t base = (size_t)nh * S_LEN * DH;
    const unsigned short* qp = qg + base;
    const unsigned short* kp = kg + base;
    const unsigned short* vp = vtg + base;        // [64][S], cols permuted per 64

    const int tid  = threadIdx.x;
    const int lane = tid & 63;
    const int w    = tid >> 6;
    const int rowg = lane & 15;
    const int og   = lane >> 4;

    const int r0 = tid >> 3,  s0 = tid & 7;
    const int r1 = r0 + 32;
    const int ldsoff0 = r0 * 128 + ((s0 * 16) ^ ((r0 & 7) << 4));
    const int ldsoff1 = r1 * 128 + ((s0 * 16) ^ ((r1 & 7) << 4));
    const int ksrc0 = r0 * 64 + s0 * 8,    ksrc1 = r1 * 64 + s0 * 8;
    const int vsrc0 = r0 * S_LEN + s0 * 8, vsrc1 = r1 * S_LEN + s0 * 8;

    short8 kr0, kr1, vr0, vr1;

    short8 qa0, qa1;
    {
        const unsigned short* qr = qp + (size_t)(q0 + 16 * w + rowg) * DH + og * 8;
        qa0 = *reinterpret_cast<const short8*>(qr);
        qa1 = *reinterpret_cast<const short8*>(qr + 32);
    }

    const f32x4 zero4 = {0.f, 0.f, 0.f, 0.f};
    f32x4 accS[4], accR[4];
    #pragma unroll
    for (int t = 0; t < 4; ++t) { accS[t] = zero4; accR[t] = zero4; }
    float dsum = 0.f;

    // ================= Phase A (k > q, softmax) — deferred-PV pipeline =============
    const int T = (S_LEN - q0) >> 6;              // phase-A tile count (>=1)
    kr0 = *(const short8*)(kp + (size_t)q0 * 64 + ksrc0);
    kr1 = *(const short8*)(kp + (size_t)q0 * 64 + ksrc1);
    vr0 = *(const short8*)(vp + q0 + vsrc0);
    vr1 = *(const short8*)(vp + q0 + vsrc1);
    *(short8*)((char*)smem + ldsoff0) = kr0;                   // K slot 0
    *(short8*)((char*)smem + ldsoff1) = kr1;
    *(short8*)((char*)(smem + 8192) + ldsoff0) = vr0;          // V slot 0
    *(short8*)((char*)(smem + 8192) + ldsoff1) = vr1;
    __syncthreads();

    short8 pa0, pa1;                              // softmax weights of previous tile
    for (int ti = 0; ti < T; ++ti) {
        const bool pf = (ti + 1 < T);
        if (pf) {
            const unsigned short* kb = kp + (size_t)(q0 + (ti + 1) * 64) * 64;
            const unsigned short* vb = vp + (q0 + (ti + 1) * 64);
            kr0 = *(const short8*)(kb + ksrc0);
            kr1 = *(const short8*)(kb + ksrc1);
            vr0 = *(const short8*)(vb + vsrc0);
            vr1 = *(const short8*)(vb + vsrc1);
        }
        const unsigned short* klds = smem + (ti & 1) * 4096;

        __builtin_amdgcn_s_setprio(1);
        // swapped QK^T for tile ti: lane owns one q (rowg), 16 k-slots
        f32x4 C[4];
        #pragma unroll
        for (int t = 0; t < 4; ++t) {
            const short8 kf0 = frag_read(klds, 16 * t + rowg, og);
            const short8 kf1 = frag_read(klds, 16 * t + rowg, og + 4);
            C[t] = mfma16(kf1, qa1, mfma16(kf0, qa0, zero4));
        }
        // PV for tile ti-1 (pa held in regs; V slot (ti-1)%3 — disjoint from writers)
        if (ti > 0) {
            const unsigned short* vprev = smem + 8192 + ((ti + 2) % 3) * 4096;
            #pragma unroll
            for (int tt = 0; tt < 4; ++tt) {
                const short8 vf0 = frag_read(vprev, 16 * tt + rowg, og);
                const short8 vf1 = frag_read(vprev, 16 * tt + rowg, og + 4);
                accS[tt] = mfma16(pa1, vf1, mfma16(pa0, vf0, accS[tt]));
            }
        }
        __builtin_amdgcn_s_setprio(0);

        if (pf) {
            unsigned short* kn = smem + ((ti + 1) & 1) * 4096;
            unsigned short* vn = smem + 8192 + ((ti + 1) % 3) * 4096;
            *(short8*)((char*)kn + ldsoff0) = kr0;
            *(short8*)((char*)kn + ldsoff1) = kr1;
            *(short8*)((char*)vn + ldsoff0) = vr0;
            *(short8*)((char*)vn + ldsoff1) = vr1;
        }
        softmax_pack(C, ti == 0, w, og, rowg, dsum, pa0, pa1);
        __syncthreads();
    }
    // drain: PV for tile T-1
    {
        const unsigned short* vprev = smem + 8192 + ((T + 2) % 3) * 4096;
        __builtin_amdgcn_s_setprio(1);
        #pragma unroll
        for (int tt = 0; tt < 4; ++tt) {
            const short8 vf0 = frag_read(vprev, 16 * tt + rowg, og);
            const short8 vf1 = frag_read(vprev, 16 * tt + rowg, og + 4);
            accS[tt] = mfma16(pa1, vf1, mfma16(pa0, vf0, accS[tt]));
        }
        __builtin_amdgcn_s_setprio(0);
    }
    __syncthreads();   // protect LDS before phase-B prologue overwrites

    // ================= Phase B (k <= q, skew) — E prefetched in registers =========
    const int jmax = q0 >> 6;

    vr0 = *(const short8*)(vp + q0 + vsrc0);
    vr1 = *(const short8*)(vp + q0 + vsrc1);
    short8 ef[8];
    #pragma unroll
    for (int t = 0; t < 4; ++t) {
        const unsigned short* er = eg + (size_t)(16 * t + rowg) * 64;
        ef[t * 2]     = *(const short8*)(er + og * 8);
        ef[t * 2 + 1] = *(const short8*)(er + (og + 4) * 8);
    }
    // zero own stripe of p slot 0 while prologue loads are in flight
    {
        const short8 z8 = {0, 0, 0, 0, 0, 0, 0, 0};
        #pragma unroll
        for (int c2 = 0; c2 < 2; ++c2) {
            const int cc = lane + 64 * c2;
            const int r = 16 * w + (cc >> 3), sc = cc & 7;
            *reinterpret_cast<short8*>((char*)smem + r * 128 + sc * 16) = z8;
        }
    }
    *(short8*)((char*)(smem + 8192) + ldsoff0) = vr0;          // V slot 0
    *(short8*)((char*)(smem + 8192) + ldsoff1) = vr1;
    __syncthreads();

    for (int j = 0; j <= jmax; ++j) {
        const bool pf = (j < jmax);
        if (pf) {
            const unsigned short* vbn = vp + (q0 - 64 * (j + 1));
            vr0 = *(const short8*)(vbn + vsrc0);
            vr1 = *(const short8*)(vbn + vsrc1);
        }
        const unsigned short* vlds = smem + 8192 + (j & 1) * 4096;

        // G = Q . Ehat (E fragments in registers)
        __builtin_amdgcn_s_setprio(1);
        f32x4 G[4];
        #pragma unroll
        for (int t = 0; t < 4; ++t)
            G[t] = mfma16(qa1, ef[t * 2 + 1], mfma16(qa0, ef[t * 2], zero4));
        __builtin_amdgcn_s_setprio(0);

        // prefetch E(j+1) fragments (consumed next iter; hides under scatter+PV)
        if (pf) {
            #pragma unroll
            for (int t = 0; t < 4; ++t) {
                const unsigned short* er = eg + (size_t)(64 * (j + 1) + 16 * t + rowg) * 64;
                ef[t * 2]     = *(const short8*)(er + og * 8);
                ef[t * 2 + 1] = *(const short8*)(er + (og + 4) * 8);
            }
        }

        unsigned short* pc = smem + (j & 1) * 4096;
        unsigned short* pn = smem + ((j + 1) & 1) * 4096;
        #pragma unroll
        for (int t = 0; t < 4; ++t) {
            const int c = 16 * t + rowg;
            #pragma unroll
            for (int r = 0; r < 4; ++r) {
                const int qq = 16 * w + og * 4 + r;
                float val = G[t][r];
                if (q0 + qq == S_LEN - 1) val += UNI;   // uniform-softmax row fold-in
                const unsigned short bv = f2bf_rn(val);
                const int swz = (qq & 7) << 4;
                if (c <= qq) {
                    const int p = pinv(qq - c);
                    *(unsigned short*)((char*)pc + qq * 128 + ((p * 2) ^ swz)) = bv;
                } else if (pf) {
                    const int p = pinv(qq - c + 64);
                    *(unsigned short*)((char*)pn + qq * 128 + ((p * 2) ^ swz)) = bv;
                }
            }
        }

        const short8 pb0 = frag_read(pc, 16 * w + rowg, og);
        const short8 pb1 = frag_read(pc, 16 * w + rowg, og + 4);
        __builtin_amdgcn_s_setprio(1);
        #pragma unroll
        for (int tt = 0; tt < 4; ++tt) {
            const short8 vf0 = frag_read(vlds, 16 * tt + rowg, og);
            const short8 vf1 = frag_read(vlds, 16 * tt + rowg, og + 4);
            accR[tt] = mfma16(pb1, vf1, mfma16(pb0, vf0, accR[tt]));
        }
        __builtin_amdgcn_s_setprio(0);

        // stage V(j+1) into slot (j+1)&1: its readers finished at the previous barrier
        if (pf) {
            unsigned short* vn = smem + 8192 + ((j + 1) & 1) * 4096;
            *(short8*)((char*)vn + ldsoff0) = vr0;
            *(short8*)((char*)vn + ldsoff1) = vr1;
        }
        __syncthreads();   // staged V visible; p traffic is intra-wave
    }

    // ================= epilogue =================
    dsum += __shfl_xor(dsum, 16);
    dsum += __shfl_xor(dsum, 32);

    const int n = nh >> 3, h = nh & 7;
    const int qrow0 = q0 + 16 * w + og * 4;
    #pragma unroll
    for (int r = 0; r < 4; ++r) {
        const int qrow = qrow0 + r;
        const float dn = __shfl(dsum, og * 4 + r);
        const float inv = (qrow == S_LEN - 1) ? 0.f : 1.f / dn;
        #pragma unroll
        for (int t = 0; t < 4; ++t) {
            const float zv = accS[t][r] * inv + accR[t][r];
            z[((size_t)n * S_LEN + qrow) * EMB + h * DH + 16 * t + rowg] = f2bf_rn(zv);
        }
    }
}

// ---------------- Kernel 3: output projection (bf16 Wo, double-buffered) ----------------
__global__ __launch_bounds__(256) void outproj_mfma(
    const unsigned short* __restrict__ z,
    const unsigned short* __restrict__ Wob, const float* __restrict__ bo,
    float* __restrict__ out)
{
    __shared__ unsigned short wo_lds[2][64 * 64];

    const int tid  = threadIdx.x;
    const int lane = tid & 63;
    const int w    = tid >> 6;
    const int rowg = lane & 15;
    const int og   = lane >> 4;

    const int nob = EMB / 64;
    const int mb = blockIdx.x / nob;
    const int ob = blockIdx.x % nob;
    const int m0 = mb * 64 + 16 * w;
    const int o0 = ob * 64;

    const int r0 = tid >> 3,  s0 = tid & 7;
    const int r1 = r0 + 32;
    const int ldsoff0 = r0 * 128 + ((s0 * 16) ^ ((r0 & 7) << 4));
    const int ldsoff1 = r1 * 128 + ((s0 * 16) ^ ((r1 & 7) << 4));
    const int wsrc0 = r0 * EMB + s0 * 8, wsrc1 = r1 * EMB + s0 * 8;
    const unsigned short* wbase = Wob + (size_t)o0 * EMB;

    f32x4 acc[4];
    #pragma unroll
    for (int t = 0; t < 4; ++t) {
        const float b = bo[o0 + 16 * t + rowg];
        acc[t] = (f32x4){b, b, b, b};
    }

    short8 wr0 = *(const short8*)(wbase + wsrc0);
    short8 wr1 = *(const short8*)(wbase + wsrc1);
    *(short8*)((char*)wo_lds[0] + ldsoff0) = wr0;
    *(short8*)((char*)wo_lds[0] + ldsoff1) = wr1;
    __syncthreads();

    int cur = 0;
    for (int kt = 0; kt < 8; ++kt) {
        const bool pf = (kt < 7);
        if (pf) {
            wr0 = *(const short8*)(wbase + (kt + 1) * 64 + wsrc0);
            wr1 = *(const short8*)(wbase + (kt + 1) * 64 + wsrc1);
        }
        const unsigned short* zr = z + (size_t)(m0 + rowg) * EMB + kt * 64;
        const short8 af0 = *reinterpret_cast<const short8*>(zr + og * 8);
        const short8 af1 = *reinterpret_cast<const short8*>(zr + 32 + og * 8);
        #pragma unroll
        for (int t = 0; t < 4; ++t) {
            acc[t] = mfma16(af0, frag_read(wo_lds[cur], 16 * t + rowg, og),     acc[t]);
            acc[t] = mfma16(af1, frag_read(wo_lds[cur], 16 * t + rowg, og + 4), acc[t]);
        }
        if (pf) {
            *(short8*)((char*)wo_lds[cur ^ 1] + ldsoff0) = wr0;
            *(short8*)((char*)wo_lds[cur ^ 1] + ldsoff1) = wr1;
        }
        __syncthreads();
        cur ^= 1;
    }

    #pragma unroll
    for (int r = 0; r < 4; ++r) {
        const size_t rowb = (size_t)(m0 + og * 4 + r) * EMB + o0;
        #pragma unroll
        for (int t = 0; t < 4; ++t)
            out[rowb + 16 * t + rowg] = acc[t][r];
    }
}

// ---------------- launch ----------------
extern "C" void kernel_launch(void* const* d_in, const int* in_sizes, int n_in,
                              void* d_out, int out_size, void* d_ws, size_t ws_size,
                              hipStream_t stream) {
    const float* x  = (const float*)d_in[0];
    const float* Wq = (const float*)d_in[1];
    const float* bq = (const float*)d_in[2];
    const float* Wk = (const float*)d_in[3];
    const float* bk = (const float*)d_in[4];
    const float* Wv = (const float*)d_in[5];
    const float* bv = (const float*)d_in[6];
    const float* E  = (const float*)d_in[7];
    const float* Wo = (const float*)d_in[8];
    const float* bo = (const float*)d_in[9];
    float* out = (float*)d_out;

    const size_t per = (size_t)NB * NH * S_LEN * DH;   // 4M elements
    unsigned short* qb  = (unsigned short*)d_ws;
    unsigned short* kb  = qb  + per;
    unsigned short* vtb = kb  + per;
    unsigned short* eb  = vtb + per;
    unsigned short* zb  = eb + (size_t)S_LEN * DH;
    unsigned short* wqb = zb + per;                    // z = NB*S*EMB = per elements
    unsigned short* wkb = wqb + 4096;
    unsigned short* wvb = wkb + 4096;
    unsigned short* wob = wvb + 4096;

    prep_we<<<(EMB * EMB + 255) / 256, 256, 0, stream>>>(Wq, Wk, Wv, Wo, E,
                                                         wqb, wkb, wvb, wob, eb);
    qkv_mfma<<<(NB * S_LEN * NH) / 64, 256, 0, stream>>>(x, wqb, bq, wkb, bk, wvb, bv,
                                                         qb, kb, vtb);
    attn_mfma<<<NB * NH * (S_LEN / 64), 256, 0, stream>>>(qb, kb, vtb, eb, zb);
    outproj_mfma<<<(NB * S_LEN / 64) * (EMB / 64), 256, 0, stream>>>(zb, wob, bo, out);
}

// Round 15
// 100.676 us; speedup vs baseline: 1.4820x; 1.4820x over previous
//
#include <hip/hip_runtime.h>
#include <hip/hip_bf16.h>

#define S_LEN 2048
#define EMB   512
#define NH    8
#define DH    64
#define NB    4

typedef float f32x4  __attribute__((ext_vector_type(4)));
typedef short short8 __attribute__((ext_vector_type(8)));
typedef short short4v __attribute__((ext_vector_type(4)));

__device__ __forceinline__ unsigned short f2bf_rn(float f) {
    return __builtin_bit_cast(unsigned short, __float2bfloat16(f));
}

__device__ __forceinline__ f32x4 mfma16(short8 a, short8 b, f32x4 c) {
    return __builtin_amdgcn_mfma_f32_16x16x32_bf16(a, b, c, 0, 0, 0);
}

// read one MFMA A/B fragment octet (8 bf16) from a swizzled 64x64 tile
__device__ __forceinline__ short8 frag_read(const unsigned short* lds, int row, int oct)
{
    const char* src = (const char*)lds + row * 128 + ((oct * 16) ^ ((row & 7) << 4));
    return *reinterpret_cast<const short8*>(src);
}

// inverse of the vT column permutation pi:
// pi(p) = (p&32) + ((p>>3)&3)*4 + (p&3) + ((p&4)?16:0)
// Note: pinv(4a+c) = pinv(4a)+c for c<4 (4-aligned quads stay contiguous).
__device__ __forceinline__ int pinv(int k) {
    return (k & 32) + ((k >> 2) & 3) * 8 + (k & 3) + ((k & 16) >> 2);
}

// stage a 64x64 bf16 tile into LDS with XOR swizzle (256 threads)
__device__ __forceinline__ void stage_tile_bf16(const unsigned short* __restrict__ g,
                                                int gstride, unsigned short* lds, int tid)
{
    #pragma unroll
    for (int c = tid; c < 512; c += 256) {
        const int r = c >> 3, s = c & 7;
        short8 v = *reinterpret_cast<const short8*>(g + (size_t)r * gstride + s * 8);
        char* dst = (char*)lds + r * 128 + ((s * 16) ^ ((r & 7) << 4));
        *reinterpret_cast<short8*>(dst) = v;
    }
}

// softmax 16 scores -> bf16 A-fragments + running denom partial (4-way tree sum)
__device__ __forceinline__ void softmax_pack(const f32x4 C[4], bool diag, int ws, int og,
                                             int rowg, float& dsum, short8& pa0, short8& pa1)
{
    constexpr float SM_SCALE = 0.04419417382415922f; // 1/sqrt(512)
    float rs[4];
    unsigned short pw[16];
    if (!diag) {
        #pragma unroll
        for (int t = 0; t < 4; ++t) {
            float a = 0.f;
            #pragma unroll
            for (int r = 0; r < 4; ++r) {
                const float wv = __expf(C[t][r] * SM_SCALE);
                a += wv;
                pw[t * 4 + r] = f2bf_rn(wv);
            }
            rs[t] = a;
        }
    } else {
        #pragma unroll
        for (int t = 0; t < 4; ++t) {
            float a = 0.f;
            #pragma unroll
            for (int r = 0; r < 4; ++r) {
                const bool keep = (t > ws) || (t == ws && (og * 4 + r) > rowg);
                const float wv = keep ? __expf(C[t][r] * SM_SCALE) : 0.f;
                a += wv;
                pw[t * 4 + r] = f2bf_rn(wv);
            }
            rs[t] = a;
        }
    }
    dsum += (rs[0] + rs[1]) + (rs[2] + rs[3]);
    #pragma unroll
    for (int i = 0; i < 8; ++i) { pa0[i] = (short)pw[i]; pa1[i] = (short)pw[8 + i]; }
}

// ---------------- Kernel 0: one-time weight+E f32->bf16 conversion ----------------
__global__ __launch_bounds__(256) void prep_we(
    const float* __restrict__ Wq, const float* __restrict__ Wk,
    const float* __restrict__ Wv, const float* __restrict__ Wo,
    const float* __restrict__ E,
    unsigned short* __restrict__ wq, unsigned short* __restrict__ wk,
    unsigned short* __restrict__ wv, unsigned short* __restrict__ wo,
    unsigned short* __restrict__ eb)
{
    const int i = blockIdx.x * 256 + threadIdx.x;
    if (i < 4096) {
        wq[i] = f2bf_rn(Wq[i]);
        wk[i] = f2bf_rn(Wk[i]);
        wv[i] = f2bf_rn(Wv[i]);
    }
    if (i < EMB * EMB) wo[i] = f2bf_rn(Wo[i]);
    if (i < S_LEN * DH) {
        const int dlt = i >> 6, d = i & 63;
        eb[i] = f2bf_rn(E[(size_t)(S_LEN - 1 - dlt) * DH + d]);
    }
}

// ------- Kernel 1: q/k/v projections via MFMA; V written TRANSPOSED (pi-permuted) -------
__global__ __launch_bounds__(256) void qkv_mfma(
    const float* __restrict__ x,
    const unsigned short* __restrict__ Wqb, const float* __restrict__ bq,
    const unsigned short* __restrict__ Wkb, const float* __restrict__ bk,
    const unsigned short* __restrict__ Wvb, const float* __restrict__ bv,
    unsigned short* __restrict__ qg, unsigned short* __restrict__ kg,
    unsigned short* __restrict__ vtg)
{
    __shared__ unsigned short w_lds[3][64 * 64];   // reused post-MFMA for V exchange

    const int tid  = threadIdx.x;
    const int lane = tid & 63;
    const int w    = tid >> 6;
    const int rowg = lane & 15;
    const int og   = lane >> 4;

    stage_tile_bf16(Wqb, 64, w_lds[0], tid);
    stage_tile_bf16(Wkb, 64, w_lds[1], tid);
    stage_tile_bf16(Wvb, 64, w_lds[2], tid);

    float bias[3][4];
    #pragma unroll
    for (int t = 0; t < 4; ++t) {
        bias[0][t] = bq[16 * t + rowg];
        bias[1][t] = bk[16 * t + rowg];
        bias[2][t] = bv[16 * t + rowg];
    }

    const int m0 = blockIdx.x * 64 + 16 * w;
    const float* xr = x + (size_t)(m0 + rowg) * 64;
    const float4 a0 = *(const float4*)(xr + og * 8);
    const float4 a1 = *(const float4*)(xr + og * 8 + 4);
    const float4 a2 = *(const float4*)(xr + 32 + og * 8);
    const float4 a3 = *(const float4*)(xr + 32 + og * 8 + 4);
    short8 af0, af1;
    af0[0] = (short)f2bf_rn(a0.x); af0[1] = (short)f2bf_rn(a0.y);
    af0[2] = (short)f2bf_rn(a0.z); af0[3] = (short)f2bf_rn(a0.w);
    af0[4] = (short)f2bf_rn(a1.x); af0[5] = (short)f2bf_rn(a1.y);
    af0[6] = (short)f2bf_rn(a1.z); af0[7] = (short)f2bf_rn(a1.w);
    af1[0] = (short)f2bf_rn(a2.x); af1[1] = (short)f2bf_rn(a2.y);
    af1[2] = (short)f2bf_rn(a2.z); af1[3] = (short)f2bf_rn(a2.w);
    af1[4] = (short)f2bf_rn(a3.x); af1[5] = (short)f2bf_rn(a3.y);
    af1[6] = (short)f2bf_rn(a3.z); af1[7] = (short)f2bf_rn(a3.w);

    __syncthreads();

    f32x4 acc[3][4];
    #pragma unroll
    for (int m = 0; m < 3; ++m)
        #pragma unroll
        for (int t = 0; t < 4; ++t) {
            const float b = bias[m][t];
            acc[m][t] = (f32x4){b, b, b, b};
        }

    #pragma unroll
    for (int m = 0; m < 3; ++m)
        #pragma unroll
        for (int t = 0; t < 4; ++t) {
            acc[m][t] = mfma16(af0, frag_read(w_lds[m], 16 * t + rowg, og),     acc[m][t]);
            acc[m][t] = mfma16(af1, frag_read(w_lds[m], 16 * t + rowg, og + 4), acc[m][t]);
        }

    // ---- write q, k (row-major bf16) ----
    unsigned short* outp[2] = {qg, kg};
    #pragma unroll
    for (int m = 0; m < 2; ++m)
        #pragma unroll
        for (int r = 0; r < 4; ++r) {
            const int mr = (blockIdx.x * 64 + 16 * w) + og * 4 + r;
            const int tk = mr >> 3, h = mr & 7;
            const int n = tk >> 11, s = tk & 2047;
            const size_t rowb = (((size_t)(n * NH + h)) * S_LEN + s) * 64;
            #pragma unroll
            for (int t = 0; t < 4; ++t)
                outp[m][rowb + 16 * t + rowg] = f2bf_rn(acc[m][t][r]);
        }

    // ---- V: LDS exchange -> transposed, pi-permuted write ----
    __syncthreads();                           // all waves done reading w_lds
    unsigned short* t_lds = w_lds[0];          // [64][72] exchange buffer
    #pragma unroll
    for (int t = 0; t < 4; ++t)
        #pragma unroll
        for (int r = 0; r < 4; ++r)
            t_lds[(16 * w + og * 4 + r) * 72 + 16 * t + rowg] = f2bf_rn(acc[2][t][r]);
    __syncthreads();

    const int tk0 = blockIdx.x * 8;            // 8 tokens per block, same n
    const int n   = tk0 >> 11;
    const int s0  = tk0 & 2047;
    const int gbase = s0 & ~63;                // 64-token pi-group base
    const int a8    = s0 & 63;                 // 8-aligned offset within group
    #pragma unroll
    for (int i = 0; i < 4; ++i) {
        const int c  = tid + 256 * i;          // 0..1023 chunk id
        const int qd = c & 1;                  // source quad within the 8 tokens
        const int d  = (c >> 1) & 63;
        const int h  = c >> 7;
        const int col = gbase + pinv(a8 + 4 * qd);
        short4v pk;
        #pragma unroll
        for (int cc = 0; cc < 4; ++cc)
            pk[cc] = (short)t_lds[((4 * qd + cc) * 8 + h) * 72 + d];
        unsigned short* dst = vtg + ((size_t)(n * NH + h) * DH + d) * S_LEN + col;
        *reinterpret_cast<short4v*>(dst) = pk;
    }
}

// ------- Kernel 2: fused MFMA attention (R13-exact: R9 structure, 40KB LDS) -------
// LDS overlay (40960 B total):
//   bytes [    0,16384): phase A K double-buffer  |  phase B p_lds double-buffer
//   bytes [16384,40960): phase A vT TRIPLE buffer
//   bytes [16384,32768): phase B vT double-buffer
//   bytes [32768,40960): phase B E single buffer (overlays V slot 2)
__global__ __launch_bounds__(256) void attn_mfma(
    const unsigned short* __restrict__ qg,
    const unsigned short* __restrict__ kg,
    const unsigned short* __restrict__ vtg,
    const unsigned short* __restrict__ eg,
    unsigned short* __restrict__ z)
{
    __shared__ __align__(16) unsigned short smem[20480];   // 40960 bytes

    constexpr float UNI = 1.0f / 2048.0f;

    const int nqt = S_LEN / 64;                   // 32
    const int bid = blockIdx.x;
    const int qt  = (nqt - 1) - (bid >> 5);       // heavy blocks first
    const int nh  = bid & 31;
    const int q0  = qt * 64;
    const size_t base = (size_t)nh * S_LEN * DH;
    const unsigned short* qp = qg + base;
    const unsigned short* kp = kg + base;
    const unsigned short* vp = vtg + base;        // [64][S], cols permuted per 64

    const int tid  = threadIdx.x;
    const int lane = tid & 63;
    const int w    = tid >> 6;
    const int rowg = lane & 15;
    const int og   = lane >> 4;

    const int r0 = tid >> 3,  s0 = tid & 7;
    const int r1 = r0 + 32;
    const int ldsoff0 = r0 * 128 + ((s0 * 16) ^ ((r0 & 7) << 4));
    const int ldsoff1 = r1 * 128 + ((s0 * 16) ^ ((r1 & 7) << 4));
    const int ksrc0 = r0 * 64 + s0 * 8,    ksrc1 = r1 * 64 + s0 * 8;
    const int vsrc0 = r0 * S_LEN + s0 * 8, vsrc1 = r1 * S_LEN + s0 * 8;

    short8 kr0, kr1, vr0, vr1;

    short8 qa0, qa1;
    {
        const unsigned short* qr = qp + (size_t)(q0 + 16 * w + rowg) * DH + og * 8;
        qa0 = *reinterpret_cast<const short8*>(qr);
        qa1 = *reinterpret_cast<const short8*>(qr + 32);
    }

    const f32x4 zero4 = {0.f, 0.f, 0.f, 0.f};
    f32x4 accS[4], accR[4];
    #pragma unroll
    for (int t = 0; t < 4; ++t) { accS[t] = zero4; accR[t] = zero4; }
    float dsum = 0.f;

    // ================= Phase A (k > q, softmax) — deferred-PV pipeline =============
    const int T = (S_LEN - q0) >> 6;              // phase-A tile count (>=1)
    kr0 = *(const short8*)(kp + (size_t)q0 * 64 + ksrc0);
    kr1 = *(const short8*)(kp + (size_t)q0 * 64 + ksrc1);
    vr0 = *(const short8*)(vp + q0 + vsrc0);
    vr1 = *(const short8*)(vp + q0 + vsrc1);
    *(short8*)((char*)smem + ldsoff0) = kr0;                   // K slot 0
    *(short8*)((char*)smem + ldsoff1) = kr1;
    *(short8*)((char*)(smem + 8192) + ldsoff0) = vr0;          // V slot 0
    *(short8*)((char*)(smem + 8192) + ldsoff1) = vr1;
    __syncthreads();

    short8 pa0, pa1;                              // softmax weights of previous tile
    for (int ti = 0; ti < T; ++ti) {
        const bool pf = (ti + 1 < T);
        if (pf) {
            const unsigned short* kb = kp + (size_t)(q0 + (ti + 1) * 64) * 64;
            const unsigned short* vb = vp + (q0 + (ti + 1) * 64);
            kr0 = *(const short8*)(kb + ksrc0);
            kr1 = *(const short8*)(kb + ksrc1);
            vr0 = *(const short8*)(vb + vsrc0);
            vr1 = *(const short8*)(vb + vsrc1);
        }
        const unsigned short* klds = smem + (ti & 1) * 4096;

        __builtin_amdgcn_s_setprio(1);
        // swapped QK^T for tile ti: lane owns one q (rowg), 16 k-slots
        f32x4 C[4];
        #pragma unroll
        for (int t = 0; t < 4; ++t) {
            const short8 kf0 = frag_read(klds, 16 * t + rowg, og);
            const short8 kf1 = frag_read(klds, 16 * t + rowg, og + 4);
            C[t] = mfma16(kf1, qa1, mfma16(kf0, qa0, zero4));
        }
        // PV for tile ti-1 (pa held in regs; V slot (ti-1)%3 — disjoint from writers)
        if (ti > 0) {
            const unsigned short* vprev = smem + 8192 + ((ti + 2) % 3) * 4096;
            #pragma unroll
            for (int tt = 0; tt < 4; ++tt) {
                const short8 vf0 = frag_read(vprev, 16 * tt + rowg, og);
                const short8 vf1 = frag_read(vprev, 16 * tt + rowg, og + 4);
                accS[tt] = mfma16(pa1, vf1, mfma16(pa0, vf0, accS[tt]));
            }
        }
        __builtin_amdgcn_s_setprio(0);

        if (pf) {
            unsigned short* kn = smem + ((ti + 1) & 1) * 4096;
            unsigned short* vn = smem + 8192 + ((ti + 1) % 3) * 4096;
            *(short8*)((char*)kn + ldsoff0) = kr0;
            *(short8*)((char*)kn + ldsoff1) = kr1;
            *(short8*)((char*)vn + ldsoff0) = vr0;
            *(short8*)((char*)vn + ldsoff1) = vr1;
        }
        softmax_pack(C, ti == 0, w, og, rowg, dsum, pa0, pa1);
        __syncthreads();
    }
    // drain: PV for tile T-1
    {
        const unsigned short* vprev = smem + 8192 + ((T + 2) % 3) * 4096;
        __builtin_amdgcn_s_setprio(1);
        #pragma unroll
        for (int tt = 0; tt < 4; ++tt) {
            const short8 vf0 = frag_read(vprev, 16 * tt + rowg, og);
            const short8 vf1 = frag_read(vprev, 16 * tt + rowg, og + 4);
            accS[tt] = mfma16(pa1, vf1, mfma16(pa0, vf0, accS[tt]));
        }
        __builtin_amdgcn_s_setprio(0);
    }
    __syncthreads();   // protect V/E region before phase-B staging overwrites

    // ================= Phase B (k <= q, skew) =================
    unsigned short* const ebuf = smem + 16384;    // bytes 32768..40960
    const int jmax = q0 >> 6;

    kr0 = *(const short8*)(eg + ksrc0);
    kr1 = *(const short8*)(eg + ksrc1);
    vr0 = *(const short8*)(vp + q0 + vsrc0);
    vr1 = *(const short8*)(vp + q0 + vsrc1);
    // zero own stripe of p_buf(0) while prologue loads are in flight
    {
        const short8 z8 = {0, 0, 0, 0, 0, 0, 0, 0};
        #pragma unroll
        for (int c2 = 0; c2 < 2; ++c2) {
            const int cc = lane + 64 * c2;
            const int r = 16 * w + (cc >> 3), sc = cc & 7;
            *reinterpret_cast<short8*>((char*)smem + r * 128 + sc * 16) = z8;
        }
    }
    *(short8*)((char*)ebuf + ldsoff0) = kr0;
    *(short8*)((char*)ebuf + ldsoff1) = kr1;
    *(short8*)((char*)(smem + 8192) + ldsoff0) = vr0;
    *(short8*)((char*)(smem + 8192) + ldsoff1) = vr1;
    __syncthreads();

    for (int j = 0; j <= jmax; ++j) {
        const bool pf = (j < jmax);
        if (pf) {
            const unsigned short* ebn = eg + (size_t)(j + 1) * 4096;
            const unsigned short* vbn = vp + (q0 - 64 * (j + 1));
            kr0 = *(const short8*)(ebn + ksrc0);
            kr1 = *(const short8*)(ebn + ksrc1);
            vr0 = *(const short8*)(vbn + vsrc0);
            vr1 = *(const short8*)(vbn + vsrc1);
        }
        const unsigned short* vlds = smem + 8192 + (j & 1) * 4096;

        // G = Q . Ehat (normal orientation): C rows = q, cols = delta
        __builtin_amdgcn_s_setprio(1);
        f32x4 G[4];
        #pragma unroll
        for (int t = 0; t < 4; ++t)
            G[t] = mfma16(qa1, frag_read(ebuf, 16 * t + rowg, og + 4),
                   mfma16(qa0, frag_read(ebuf, 16 * t + rowg, og), zero4));
        __builtin_amdgcn_s_setprio(0);

        unsigned short* pc = smem + (j & 1) * 4096;
        unsigned short* pn = smem + ((j + 1) & 1) * 4096;
        #pragma unroll
        for (int t = 0; t < 4; ++t) {
            const int c = 16 * t + rowg;
            #pragma unroll
            for (int r = 0; r < 4; ++r) {
                const int qq = 16 * w + og * 4 + r;
                float val = G[t][r];
                if (q0 + qq == S_LEN - 1) val += UNI;   // uniform-softmax row fold-in
                const unsigned short bv = f2bf_rn(val);
                const int swz = (qq & 7) << 4;
                if (c <= qq) {
                    const int p = pinv(qq - c);
                    *(unsigned short*)((char*)pc + qq * 128 + ((p * 2) ^ swz)) = bv;
                } else if (pf) {
                    const int p = pinv(qq - c + 64);
                    *(unsigned short*)((char*)pn + qq * 128 + ((p * 2) ^ swz)) = bv;
                }
            }
        }

        const short8 pb0 = frag_read(pc, 16 * w + rowg, og);
        const short8 pb1 = frag_read(pc, 16 * w + rowg, og + 4);
        __builtin_amdgcn_s_setprio(1);
        #pragma unroll
        for (int tt = 0; tt < 4; ++tt) {
            const short8 vf0 = frag_read(vlds, 16 * tt + rowg, og);
            const short8 vf1 = frag_read(vlds, 16 * tt + rowg, og + 4);
            accR[tt] = mfma16(pb1, vf1, mfma16(pb0, vf0, accR[tt]));
        }
        __builtin_amdgcn_s_setprio(0);

        __syncthreads();                 // B1: all waves done reading ebuf & vlds
        if (pf) {
            unsigned short* vn = smem + 8192 + ((j + 1) & 1) * 4096;
            *(short8*)((char*)ebuf + ldsoff0) = kr0;
            *(short8*)((char*)ebuf + ldsoff1) = kr1;
            *(short8*)((char*)vn + ldsoff0) = vr0;
            *(short8*)((char*)vn + ldsoff1) = vr1;
            __syncthreads();             // B2: staged E/V visible before next iter
        }
    }

    // ================= epilogue =================
    dsum += __shfl_xor(dsum, 16);
    dsum += __shfl_xor(dsum, 32);

    const int n = nh >> 3, h = nh & 7;
    const int qrow0 = q0 + 16 * w + og * 4;
    #pragma unroll
    for (int r = 0; r < 4; ++r) {
        const int qrow = qrow0 + r;
        const float dn = __shfl(dsum, og * 4 + r);
        const float inv = (qrow == S_LEN - 1) ? 0.f : 1.f / dn;
        #pragma unroll
        for (int t = 0; t < 4; ++t) {
            const float zv = accS[t][r] * inv + accR[t][r];
            z[((size_t)n * S_LEN + qrow) * EMB + h * DH + 16 * t + rowg] = f2bf_rn(zv);
        }
    }
}

// ---------------- Kernel 3: output projection (bf16 Wo, double-buffered) ----------------
__global__ __launch_bounds__(256) void outproj_mfma(
    const unsigned short* __restrict__ z,
    const unsigned short* __restrict__ Wob, const float* __restrict__ bo,
    float* __restrict__ out)
{
    __shared__ unsigned short wo_lds[2][64 * 64];

    const int tid  = threadIdx.x;
    const int lane = tid & 63;
    const int w    = tid >> 6;
    const int rowg = lane & 15;
    const int og   = lane >> 4;

    const int nob = EMB / 64;
    const int mb = blockIdx.x / nob;
    const int ob = blockIdx.x % nob;
    const int m0 = mb * 64 + 16 * w;
    const int o0 = ob * 64;

    const int r0 = tid >> 3,  s0 = tid & 7;
    const int r1 = r0 + 32;
    const int ldsoff0 = r0 * 128 + ((s0 * 16) ^ ((r0 & 7) << 4));
    const int ldsoff1 = r1 * 128 + ((s0 * 16) ^ ((r1 & 7) << 4));
    const int wsrc0 = r0 * EMB + s0 * 8, wsrc1 = r1 * EMB + s0 * 8;
    const unsigned short* wbase = Wob + (size_t)o0 * EMB;

    f32x4 acc[4];
    #pragma unroll
    for (int t = 0; t < 4; ++t) {
        const float b = bo[o0 + 16 * t + rowg];
        acc[t] = (f32x4){b, b, b, b};
    }

    short8 wr0 = *(const short8*)(wbase + wsrc0);
    short8 wr1 = *(const short8*)(wbase + wsrc1);
    *(short8*)((char*)wo_lds[0] + ldsoff0) = wr0;
    *(short8*)((char*)wo_lds[0] + ldsoff1) = wr1;
    __syncthreads();

    int cur = 0;
    for (int kt = 0; kt < 8; ++kt) {
        const bool pf = (kt < 7);
        if (pf) {
            wr0 = *(const short8*)(wbase + (kt + 1) * 64 + wsrc0);
            wr1 = *(const short8*)(wbase + (kt + 1) * 64 + wsrc1);
        }
        const unsigned short* zr = z + (size_t)(m0 + rowg) * EMB + kt * 64;
        const short8 af0 = *reinterpret_cast<const short8*>(zr + og * 8);
        const short8 af1 = *reinterpret_cast<const short8*>(zr + 32 + og * 8);
        #pragma unroll
        for (int t = 0; t < 4; ++t) {
            acc[t] = mfma16(af0, frag_read(wo_lds[cur], 16 * t + rowg, og),     acc[t]);
            acc[t] = mfma16(af1, frag_read(wo_lds[cur], 16 * t + rowg, og + 4), acc[t]);
        }
        if (pf) {
            *(short8*)((char*)wo_lds[cur ^ 1] + ldsoff0) = wr0;
            *(short8*)((char*)wo_lds[cur ^ 1] + ldsoff1) = wr1;
        }
        __syncthreads();
        cur ^= 1;
    }

    #pragma unroll
    for (int r = 0; r < 4; ++r) {
        const size_t rowb = (size_t)(m0 + og * 4 + r) * EMB + o0;
        #pragma unroll
        for (int t = 0; t < 4; ++t)
            out[rowb + 16 * t + rowg] = acc[t][r];
    }
}

// ---------------- launch ----------------
extern "C" void kernel_launch(void* const* d_in, const int* in_sizes, int n_in,
                              void* d_out, int out_size, void* d_ws, size_t ws_size,
                              hipStream_t stream) {
    const float* x  = (const float*)d_in[0];
    const float* Wq = (const float*)d_in[1];
    const float* bq = (const float*)d_in[2];
    const float* Wk = (const float*)d_in[3];
    const float* bk = (const float*)d_in[4];
    const float* Wv = (const float*)d_in[5];
    const float* bv = (const float*)d_in[6];
    const float* E  = (const float*)d_in[7];
    const float* Wo = (const float*)d_in[8];
    const float* bo = (const float*)d_in[9];
    float* out = (float*)d_out;

    const size_t per = (size_t)NB * NH * S_LEN * DH;   // 4M elements
    unsigned short* qb  = (unsigned short*)d_ws;
    unsigned short* kb  = qb  + per;
    unsigned short* vtb = kb  + per;
    unsigned short* eb  = vtb + per;
    unsigned short* zb  = eb + (size_t)S_LEN * DH;
    unsigned short* wqb = zb + per;                    // z = NB*S*EMB = per elements
    unsigned short* wkb = wqb + 4096;
    unsigned short* wvb = wkb + 4096;
    unsigned short* wob = wvb + 4096;

    prep_we<<<(EMB * EMB + 255) / 256, 256, 0, stream>>>(Wq, Wk, Wv, Wo, E,
                                                         wqb, wkb, wvb, wob, eb);
    qkv_mfma<<<(NB * S_LEN * NH) / 64, 256, 0, stream>>>(x, wqb, bq, wkb, bk, wvb, bv,
                                                         qb, kb, vtb);
    attn_mfma<<<NB * NH * (S_LEN / 64), 256, 0, stream>>>(qb, kb, vtb, eb, zb);
    outproj_mfma<<<(NB * S_LEN / 64) * (EMB / 64), 256, 0, stream>>>(zb, wob, bo, out);
}

// Round 16
// 100.609 us; speedup vs baseline: 1.4830x; 1.0007x over previous
//
#include <hip/hip_runtime.h>
#include <hip/hip_bf16.h>

#define S_LEN 2048
#define EMB   512
#define NH    8
#define DH    64
#define NB    4

typedef float f32x4  __attribute__((ext_vector_type(4)));
typedef short short8 __attribute__((ext_vector_type(8)));
typedef short short4v __attribute__((ext_vector_type(4)));

__device__ __forceinline__ unsigned short f2bf_rn(float f) {
    return __builtin_bit_cast(unsigned short, __float2bfloat16(f));
}

__device__ __forceinline__ f32x4 mfma16(short8 a, short8 b, f32x4 c) {
    return __builtin_amdgcn_mfma_f32_16x16x32_bf16(a, b, c, 0, 0, 0);
}

// read one MFMA A/B fragment octet (8 bf16) from a swizzled 64x64 tile
__device__ __forceinline__ short8 frag_read(const unsigned short* lds, int row, int oct)
{
    const char* src = (const char*)lds + row * 128 + ((oct * 16) ^ ((row & 7) << 4));
    return *reinterpret_cast<const short8*>(src);
}

// inverse of the vT column permutation pi:
// pi(p) = (p&32) + ((p>>3)&3)*4 + (p&3) + ((p&4)?16:0)
// Note: pinv(4a+c) = pinv(4a)+c for c<4 (4-aligned quads stay contiguous).
__device__ __forceinline__ int pinv(int k) {
    return (k & 32) + ((k >> 2) & 3) * 8 + (k & 3) + ((k & 16) >> 2);
}

// stage a 64x64 bf16 tile into LDS with XOR swizzle (256 threads)
__device__ __forceinline__ void stage_tile_bf16(const unsigned short* __restrict__ g,
                                                int gstride, unsigned short* lds, int tid)
{
    #pragma unroll
    for (int c = tid; c < 512; c += 256) {
        const int r = c >> 3, s = c & 7;
        short8 v = *reinterpret_cast<const short8*>(g + (size_t)r * gstride + s * 8);
        char* dst = (char*)lds + r * 128 + ((s * 16) ^ ((r & 7) << 4));
        *reinterpret_cast<short8*>(dst) = v;
    }
}

// softmax 16 scores -> bf16 A-fragments + running denom partial (4-way tree sum)
__device__ __forceinline__ void softmax_pack(const f32x4 C[4], bool diag, int ws, int og,
                                             int rowg, float& dsum, short8& pa0, short8& pa1)
{
    constexpr float SM_SCALE = 0.04419417382415922f; // 1/sqrt(512)
    float rs[4];
    unsigned short pw[16];
    if (!diag) {
        #pragma unroll
        for (int t = 0; t < 4; ++t) {
            float a = 0.f;
            #pragma unroll
            for (int r = 0; r < 4; ++r) {
                const float wv = __expf(C[t][r] * SM_SCALE);
                a += wv;
                pw[t * 4 + r] = f2bf_rn(wv);
            }
            rs[t] = a;
        }
    } else {
        #pragma unroll
        for (int t = 0; t < 4; ++t) {
            float a = 0.f;
            #pragma unroll
            for (int r = 0; r < 4; ++r) {
                const bool keep = (t > ws) || (t == ws && (og * 4 + r) > rowg);
                const float wv = keep ? __expf(C[t][r] * SM_SCALE) : 0.f;
                a += wv;
                pw[t * 4 + r] = f2bf_rn(wv);
            }
            rs[t] = a;
        }
    }
    dsum += (rs[0] + rs[1]) + (rs[2] + rs[3]);
    #pragma unroll
    for (int i = 0; i < 8; ++i) { pa0[i] = (short)pw[i]; pa1[i] = (short)pw[8 + i]; }
}

// ---------------- Kernel 0: one-time weight+E f32->bf16 conversion ----------------
__global__ __launch_bounds__(256) void prep_we(
    const float* __restrict__ Wq, const float* __restrict__ Wk,
    const float* __restrict__ Wv, const float* __restrict__ Wo,
    const float* __restrict__ E,
    unsigned short* __restrict__ wq, unsigned short* __restrict__ wk,
    unsigned short* __restrict__ wv, unsigned short* __restrict__ wo,
    unsigned short* __restrict__ eb)
{
    const int i = blockIdx.x * 256 + threadIdx.x;
    if (i < 4096) {
        wq[i] = f2bf_rn(Wq[i]);
        wk[i] = f2bf_rn(Wk[i]);
        wv[i] = f2bf_rn(Wv[i]);
    }
    if (i < EMB * EMB) wo[i] = f2bf_rn(Wo[i]);
    if (i < S_LEN * DH) {
        const int dlt = i >> 6, d = i & 63;
        eb[i] = f2bf_rn(E[(size_t)(S_LEN - 1 - dlt) * DH + d]);
    }
}

// ------- Kernel 1: q/k/v projections via MFMA; V written TRANSPOSED (pi-permuted) -------
__global__ __launch_bounds__(256) void qkv_mfma(
    const float* __restrict__ x,
    const unsigned short* __restrict__ Wqb, const float* __restrict__ bq,
    const unsigned short* __restrict__ Wkb, const float* __restrict__ bk,
    const unsigned short* __restrict__ Wvb, const float* __restrict__ bv,
    unsigned short* __restrict__ qg, unsigned short* __restrict__ kg,
    unsigned short* __restrict__ vtg)
{
    __shared__ unsigned short w_lds[3][64 * 64];   // reused post-MFMA for V exchange

    const int tid  = threadIdx.x;
    const int lane = tid & 63;
    const int w    = tid >> 6;
    const int rowg = lane & 15;
    const int og   = lane >> 4;

    stage_tile_bf16(Wqb, 64, w_lds[0], tid);
    stage_tile_bf16(Wkb, 64, w_lds[1], tid);
    stage_tile_bf16(Wvb, 64, w_lds[2], tid);

    float bias[3][4];
    #pragma unroll
    for (int t = 0; t < 4; ++t) {
        bias[0][t] = bq[16 * t + rowg];
        bias[1][t] = bk[16 * t + rowg];
        bias[2][t] = bv[16 * t + rowg];
    }

    const int m0 = blockIdx.x * 64 + 16 * w;
    const float* xr = x + (size_t)(m0 + rowg) * 64;
    const float4 a0 = *(const float4*)(xr + og * 8);
    const float4 a1 = *(const float4*)(xr + og * 8 + 4);
    const float4 a2 = *(const float4*)(xr + 32 + og * 8);
    const float4 a3 = *(const float4*)(xr + 32 + og * 8 + 4);
    short8 af0, af1;
    af0[0] = (short)f2bf_rn(a0.x); af0[1] = (short)f2bf_rn(a0.y);
    af0[2] = (short)f2bf_rn(a0.z); af0[3] = (short)f2bf_rn(a0.w);
    af0[4] = (short)f2bf_rn(a1.x); af0[5] = (short)f2bf_rn(a1.y);
    af0[6] = (short)f2bf_rn(a1.z); af0[7] = (short)f2bf_rn(a1.w);
    af1[0] = (short)f2bf_rn(a2.x); af1[1] = (short)f2bf_rn(a2.y);
    af1[2] = (short)f2bf_rn(a2.z); af1[3] = (short)f2bf_rn(a2.w);
    af1[4] = (short)f2bf_rn(a3.x); af1[5] = (short)f2bf_rn(a3.y);
    af1[6] = (short)f2bf_rn(a3.z); af1[7] = (short)f2bf_rn(a3.w);

    __syncthreads();

    f32x4 acc[3][4];
    #pragma unroll
    for (int m = 0; m < 3; ++m)
        #pragma unroll
        for (int t = 0; t < 4; ++t) {
            const float b = bias[m][t];
            acc[m][t] = (f32x4){b, b, b, b};
        }

    #pragma unroll
    for (int m = 0; m < 3; ++m)
        #pragma unroll
        for (int t = 0; t < 4; ++t) {
            acc[m][t] = mfma16(af0, frag_read(w_lds[m], 16 * t + rowg, og),     acc[m][t]);
            acc[m][t] = mfma16(af1, frag_read(w_lds[m], 16 * t + rowg, og + 4), acc[m][t]);
        }

    // ---- write q, k (row-major bf16) ----
    unsigned short* outp[2] = {qg, kg};
    #pragma unroll
    for (int m = 0; m < 2; ++m)
        #pragma unroll
        for (int r = 0; r < 4; ++r) {
            const int mr = (blockIdx.x * 64 + 16 * w) + og * 4 + r;
            const int tk = mr >> 3, h = mr & 7;
            const int n = tk >> 11, s = tk & 2047;
            const size_t rowb = (((size_t)(n * NH + h)) * S_LEN + s) * 64;
            #pragma unroll
            for (int t = 0; t < 4; ++t)
                outp[m][rowb + 16 * t + rowg] = f2bf_rn(acc[m][t][r]);
        }

    // ---- V: LDS exchange -> transposed, pi-permuted write ----
    __syncthreads();                           // all waves done reading w_lds
    unsigned short* t_lds = w_lds[0];          // [64][72] exchange buffer
    #pragma unroll
    for (int t = 0; t < 4; ++t)
        #pragma unroll
        for (int r = 0; r < 4; ++r)
            t_lds[(16 * w + og * 4 + r) * 72 + 16 * t + rowg] = f2bf_rn(acc[2][t][r]);
    __syncthreads();

    const int tk0 = blockIdx.x * 8;            // 8 tokens per block, same n
    const int n   = tk0 >> 11;
    const int s0  = tk0 & 2047;
    const int gbase = s0 & ~63;                // 64-token pi-group base
    const int a8    = s0 & 63;                 // 8-aligned offset within group
    #pragma unroll
    for (int i = 0; i < 4; ++i) {
        const int c  = tid + 256 * i;          // 0..1023 chunk id
        const int qd = c & 1;                  // source quad within the 8 tokens
        const int d  = (c >> 1) & 63;
        const int h  = c >> 7;
        const int col = gbase + pinv(a8 + 4 * qd);
        short4v pk;
        #pragma unroll
        for (int cc = 0; cc < 4; ++cc)
            pk[cc] = (short)t_lds[((4 * qd + cc) * 8 + h) * 72 + d];
        unsigned short* dst = vtg + ((size_t)(n * NH + h) * DH + d) * S_LEN + col;
        *reinterpret_cast<short4v*>(dst) = pk;
    }
}

// ------- Kernel 2: fused MFMA attention (R13-exact: R9 structure, 40KB LDS) -------
// LDS overlay (40960 B total):
//   bytes [    0,16384): phase A K double-buffer  |  phase B p_lds double-buffer
//   bytes [16384,40960): phase A vT TRIPLE buffer
//   bytes [16384,32768): phase B vT double-buffer
//   bytes [32768,40960): phase B E single buffer (overlays V slot 2)
__global__ __launch_bounds__(256) void attn_mfma(
    const unsigned short* __restrict__ qg,
    const unsigned short* __restrict__ kg,
    const unsigned short* __restrict__ vtg,
    const unsigned short* __restrict__ eg,
    unsigned short* __restrict__ z)
{
    __shared__ __align__(16) unsigned short smem[20480];   // 40960 bytes

    constexpr float UNI = 1.0f / 2048.0f;

    const int nqt = S_LEN / 64;                   // 32
    const int bid = blockIdx.x;
    const int qt  = (nqt - 1) - (bid >> 5);       // heavy blocks first
    const int nh  = bid & 31;
    const int q0  = qt * 64;
    const size_t base = (size_t)nh * S_LEN * DH;
    const unsigned short* qp = qg + base;
    const unsigned short* kp = kg + base;
    const unsigned short* vp = vtg + base;        // [64][S], cols permuted per 64

    const int tid  = threadIdx.x;
    const int lane = tid & 63;
    const int w    = tid >> 6;
    const int rowg = lane & 15;
    const int og   = lane >> 4;

    const int r0 = tid >> 3,  s0 = tid & 7;
    const int r1 = r0 + 32;
    const int ldsoff0 = r0 * 128 + ((s0 * 16) ^ ((r0 & 7) << 4));
    const int ldsoff1 = r1 * 128 + ((s0 * 16) ^ ((r1 & 7) << 4));
    const int ksrc0 = r0 * 64 + s0 * 8,    ksrc1 = r1 * 64 + s0 * 8;
    const int vsrc0 = r0 * S_LEN + s0 * 8, vsrc1 = r1 * S_LEN + s0 * 8;

    short8 kr0, kr1, vr0, vr1;

    short8 qa0, qa1;
    {
        const unsigned short* qr = qp + (size_t)(q0 + 16 * w + rowg) * DH + og * 8;
        qa0 = *reinterpret_cast<const short8*>(qr);
        qa1 = *reinterpret_cast<const short8*>(qr + 32);
    }

    const f32x4 zero4 = {0.f, 0.f, 0.f, 0.f};
    f32x4 accS[4], accR[4];
    #pragma unroll
    for (int t = 0; t < 4; ++t) { accS[t] = zero4; accR[t] = zero4; }
    float dsum = 0.f;

    // ================= Phase A (k > q, softmax) — deferred-PV pipeline =============
    const int T = (S_LEN - q0) >> 6;              // phase-A tile count (>=1)
    kr0 = *(const short8*)(kp + (size_t)q0 * 64 + ksrc0);
    kr1 = *(const short8*)(kp + (size_t)q0 * 64 + ksrc1);
    vr0 = *(const short8*)(vp + q0 + vsrc0);
    vr1 = *(const short8*)(vp + q0 + vsrc1);
    *(short8*)((char*)smem + ldsoff0) = kr0;                   // K slot 0
    *(short8*)((char*)smem + ldsoff1) = kr1;
    *(short8*)((char*)(smem + 8192) + ldsoff0) = vr0;          // V slot 0
    *(short8*)((char*)(smem + 8192) + ldsoff1) = vr1;
    __syncthreads();

    short8 pa0, pa1;                              // softmax weights of previous tile
    for (int ti = 0; ti < T; ++ti) {
        const bool pf = (ti + 1 < T);
        if (pf) {
            const unsigned short* kb = kp + (size_t)(q0 + (ti + 1) * 64) * 64;
            const unsigned short* vb = vp + (q0 + (ti + 1) * 64);
            kr0 = *(const short8*)(kb + ksrc0);
            kr1 = *(const short8*)(kb + ksrc1);
            vr0 = *(const short8*)(vb + vsrc0);
            vr1 = *(const short8*)(vb + vsrc1);
        }
        const unsigned short* klds = smem + (ti & 1) * 4096;

        __builtin_amdgcn_s_setprio(1);
        // swapped QK^T for tile ti: lane owns one q (rowg), 16 k-slots
        f32x4 C[4];
        #pragma unroll
        for (int t = 0; t < 4; ++t) {
            const short8 kf0 = frag_read(klds, 16 * t + rowg, og);
            const short8 kf1 = frag_read(klds, 16 * t + rowg, og + 4);
            C[t] = mfma16(kf1, qa1, mfma16(kf0, qa0, zero4));
        }
        // PV for tile ti-1 (pa held in regs; V slot (ti-1)%3 — disjoint from writers)
        if (ti > 0) {
            const unsigned short* vprev = smem + 8192 + ((ti + 2) % 3) * 4096;
            #pragma unroll
            for (int tt = 0; tt < 4; ++tt) {
                const short8 vf0 = frag_read(vprev, 16 * tt + rowg, og);
                const short8 vf1 = frag_read(vprev, 16 * tt + rowg, og + 4);
                accS[tt] = mfma16(pa1, vf1, mfma16(pa0, vf0, accS[tt]));
            }
        }
        __builtin_amdgcn_s_setprio(0);

        if (pf) {
            unsigned short* kn = smem + ((ti + 1) & 1) * 4096;
            unsigned short* vn = smem + 8192 + ((ti + 1) % 3) * 4096;
            *(short8*)((char*)kn + ldsoff0) = kr0;
            *(short8*)((char*)kn + ldsoff1) = kr1;
            *(short8*)((char*)vn + ldsoff0) = vr0;
            *(short8*)((char*)vn + ldsoff1) = vr1;
        }
        softmax_pack(C, ti == 0, w, og, rowg, dsum, pa0, pa1);
        __syncthreads();
    }
    // drain: PV for tile T-1
    {
        const unsigned short* vprev = smem + 8192 + ((T + 2) % 3) * 4096;
        __builtin_amdgcn_s_setprio(1);
        #pragma unroll
        for (int tt = 0; tt < 4; ++tt) {
            const short8 vf0 = frag_read(vprev, 16 * tt + rowg, og);
            const short8 vf1 = frag_read(vprev, 16 * tt + rowg, og + 4);
            accS[tt] = mfma16(pa1, vf1, mfma16(pa0, vf0, accS[tt]));
        }
        __builtin_amdgcn_s_setprio(0);
    }
    __syncthreads();   // protect V/E region before phase-B staging overwrites

    // ================= Phase B (k <= q, skew) =================
    unsigned short* const ebuf = smem + 16384;    // bytes 32768..40960
    const int jmax = q0 >> 6;

    kr0 = *(const short8*)(eg + ksrc0);
    kr1 = *(const short8*)(eg + ksrc1);
    vr0 = *(const short8*)(vp + q0 + vsrc0);
    vr1 = *(const short8*)(vp + q0 + vsrc1);
    // zero own stripe of p_buf(0) while prologue loads are in flight
    {
        const short8 z8 = {0, 0, 0, 0, 0, 0, 0, 0};
        #pragma unroll
        for (int c2 = 0; c2 < 2; ++c2) {
            const int cc = lane + 64 * c2;
            const int r = 16 * w + (cc >> 3), sc = cc & 7;
            *reinterpret_cast<short8*>((char*)smem + r * 128 + sc * 16) = z8;
        }
    }
    *(short8*)((char*)ebuf + ldsoff0) = kr0;
    *(short8*)((char*)ebuf + ldsoff1) = kr1;
    *(short8*)((char*)(smem + 8192) + ldsoff0) = vr0;
    *(short8*)((char*)(smem + 8192) + ldsoff1) = vr1;
    __syncthreads();

    for (int j = 0; j <= jmax; ++j) {
        const bool pf = (j < jmax);
        if (pf) {
            const unsigned short* ebn = eg + (size_t)(j + 1) * 4096;
            const unsigned short* vbn = vp + (q0 - 64 * (j + 1));
            kr0 = *(const short8*)(ebn + ksrc0);
            kr1 = *(const short8*)(ebn + ksrc1);
            vr0 = *(const short8*)(vbn + vsrc0);
            vr1 = *(const short8*)(vbn + vsrc1);
        }
        const unsigned short* vlds = smem + 8192 + (j & 1) * 4096;

        // G = Q . Ehat (normal orientation): C rows = q, cols = delta
        __builtin_amdgcn_s_setprio(1);
        f32x4 G[4];
        #pragma unroll
        for (int t = 0; t < 4; ++t)
            G[t] = mfma16(qa1, frag_read(ebuf, 16 * t + rowg, og + 4),
                   mfma16(qa0, frag_read(ebuf, 16 * t + rowg, og), zero4));
        __builtin_amdgcn_s_setprio(0);

        unsigned short* pc = smem + (j & 1) * 4096;
        unsigned short* pn = smem + ((j + 1) & 1) * 4096;
        #pragma unroll
        for (int t = 0; t < 4; ++t) {
            const int c = 16 * t + rowg;
            #pragma unroll
            for (int r = 0; r < 4; ++r) {
                const int qq = 16 * w + og * 4 + r;
                float val = G[t][r];
                if (q0 + qq == S_LEN - 1) val += UNI;   // uniform-softmax row fold-in
                const unsigned short bv = f2bf_rn(val);
                const int swz = (qq & 7) << 4;
                if (c <= qq) {
                    const int p = pinv(qq - c);
                    *(unsigned short*)((char*)pc + qq * 128 + ((p * 2) ^ swz)) = bv;
                } else if (pf) {
                    const int p = pinv(qq - c + 64);
                    *(unsigned short*)((char*)pn + qq * 128 + ((p * 2) ^ swz)) = bv;
                }
            }
        }

        const short8 pb0 = frag_read(pc, 16 * w + rowg, og);
        const short8 pb1 = frag_read(pc, 16 * w + rowg, og + 4);
        __builtin_amdgcn_s_setprio(1);
        #pragma unroll
        for (int tt = 0; tt < 4; ++tt) {
            const short8 vf0 = frag_read(vlds, 16 * tt + rowg, og);
            const short8 vf1 = frag_read(vlds, 16 * tt + rowg, og + 4);
            accR[tt] = mfma16(pb1, vf1, mfma16(pb0, vf0, accR[tt]));
        }
        __builtin_amdgcn_s_setprio(0);

        __syncthreads();                 // B1: all waves done reading ebuf & vlds
        if (pf) {
            unsigned short* vn = smem + 8192 + ((j + 1) & 1) * 4096;
            *(short8*)((char*)ebuf + ldsoff0) = kr0;
            *(short8*)((char*)ebuf + ldsoff1) = kr1;
            *(short8*)((char*)vn + ldsoff0) = vr0;
            *(short8*)((char*)vn + ldsoff1) = vr1;
            __syncthreads();             // B2: staged E/V visible before next iter
        }
    }

    // ================= epilogue =================
    dsum += __shfl_xor(dsum, 16);
    dsum += __shfl_xor(dsum, 32);

    const int n = nh >> 3, h = nh & 7;
    const int qrow0 = q0 + 16 * w + og * 4;
    #pragma unroll
    for (int r = 0; r < 4; ++r) {
        const int qrow = qrow0 + r;
        const float dn = __shfl(dsum, og * 4 + r);
        const float inv = (qrow == S_LEN - 1) ? 0.f : 1.f / dn;
        #pragma unroll
        for (int t = 0; t < 4; ++t) {
            const float zv = accS[t][r] * inv + accR[t][r];
            z[((size_t)n * S_LEN + qrow) * EMB + h * DH + 16 * t + rowg] = f2bf_rn(zv);
        }
    }
}

// ---- Kernel 3: output projection (bf16 Wo, double-buffered, 2 m-tiles/block) ----
__global__ __launch_bounds__(256) void outproj_mfma(
    const unsigned short* __restrict__ z,
    const unsigned short* __restrict__ Wob, const float* __restrict__ bo,
    float* __restrict__ out)
{
    __shared__ unsigned short wo_lds[2][64 * 64];

    const int tid  = threadIdx.x;
    const int lane = tid & 63;
    const int w    = tid >> 6;
    const int rowg = lane & 15;
    const int og   = lane >> 4;

    const int nob = EMB / 64;                  // 8
    const int mb = blockIdx.x / nob;           // 0..63 (128-token tiles)
    const int ob = blockIdx.x % nob;
    const int m0 = mb * 128 + 16 * w;
    const int o0 = ob * 64;

    const int r0 = tid >> 3,  s0 = tid & 7;
    const int r1 = r0 + 32;
    const int ldsoff0 = r0 * 128 + ((s0 * 16) ^ ((r0 & 7) << 4));
    const int ldsoff1 = r1 * 128 + ((s0 * 16) ^ ((r1 & 7) << 4));
    const int wsrc0 = r0 * EMB + s0 * 8, wsrc1 = r1 * EMB + s0 * 8;
    const unsigned short* wbase = Wob + (size_t)o0 * EMB;

    f32x4 acc[2][4];
    #pragma unroll
    for (int t = 0; t < 4; ++t) {
        const float b = bo[o0 + 16 * t + rowg];
        acc[0][t] = (f32x4){b, b, b, b};
        acc[1][t] = (f32x4){b, b, b, b};
    }

    short8 wr0 = *(const short8*)(wbase + wsrc0);
    short8 wr1 = *(const short8*)(wbase + wsrc1);
    *(short8*)((char*)wo_lds[0] + ldsoff0) = wr0;
    *(short8*)((char*)wo_lds[0] + ldsoff1) = wr1;
    __syncthreads();

    int cur = 0;
    for (int kt = 0; kt < 8; ++kt) {
        const bool pf = (kt < 7);
        if (pf) {
            wr0 = *(const short8*)(wbase + (kt + 1) * 64 + wsrc0);
            wr1 = *(const short8*)(wbase + (kt + 1) * 64 + wsrc1);
        }
        #pragma unroll
        for (int s = 0; s < 2; ++s) {
            const unsigned short* zr = z + (size_t)(m0 + 64 * s + rowg) * EMB + kt * 64;
            const short8 af0 = *reinterpret_cast<const short8*>(zr + og * 8);
            const short8 af1 = *reinterpret_cast<const short8*>(zr + 32 + og * 8);
            #pragma unroll
            for (int t = 0; t < 4; ++t) {
                acc[s][t] = mfma16(af0, frag_read(wo_lds[cur], 16 * t + rowg, og),     acc[s][t]);
                acc[s][t] = mfma16(af1, frag_read(wo_lds[cur], 16 * t + rowg, og + 4), acc[s][t]);
            }
        }
        if (pf) {
            *(short8*)((char*)wo_lds[cur ^ 1] + ldsoff0) = wr0;
            *(short8*)((char*)wo_lds[cur ^ 1] + ldsoff1) = wr1;
        }
        __syncthreads();
        cur ^= 1;
    }

    #pragma unroll
    for (int s = 0; s < 2; ++s)
        #pragma unroll
        for (int r = 0; r < 4; ++r) {
            const size_t rowb = (size_t)(m0 + 64 * s + og * 4 + r) * EMB + o0;
            #pragma unroll
            for (int t = 0; t < 4; ++t)
                out[rowb + 16 * t + rowg] = acc[s][t][r];
        }
}

// ---------------- launch ----------------
extern "C" void kernel_launch(void* const* d_in, const int* in_sizes, int n_in,
                              void* d_out, int out_size, void* d_ws, size_t ws_size,
                              hipStream_t stream) {
    const float* x  = (const float*)d_in[0];
    const float* Wq = (const float*)d_in[1];
    const float* bq = (const float*)d_in[2];
    const float* Wk = (const float*)d_in[3];
    const float* bk = (const float*)d_in[4];
    const float* Wv = (const float*)d_in[5];
    const float* bv = (const float*)d_in[6];
    const float* E  = (const float*)d_in[7];
    const float* Wo = (const float*)d_in[8];
    const float* bo = (const float*)d_in[9];
    float* out = (float*)d_out;

    const size_t per = (size_t)NB * NH * S_LEN * DH;   // 4M elements
    unsigned short* qb  = (unsigned short*)d_ws;
    unsigned short* kb  = qb  + per;
    unsigned short* vtb = kb  + per;
    unsigned short* eb  = vtb + per;
    unsigned short* zb  = eb + (size_t)S_LEN * DH;
    unsigned short* wqb = zb + per;                    // z = NB*S*EMB = per elements
    unsigned short* wkb = wqb + 4096;
    unsigned short* wvb = wkb + 4096;
    unsigned short* wob = wvb + 4096;

    prep_we<<<(EMB * EMB + 255) / 256, 256, 0, stream>>>(Wq, Wk, Wv, Wo, E,
                                                         wqb, wkb, wvb, wob, eb);
    qkv_mfma<<<(NB * S_LEN * NH) / 64, 256, 0, stream>>>(x, wqb, bq, wkb, bk, wvb, bv,
                                                         qb, kb, vtb);
    attn_mfma<<<NB * NH * (S_LEN / 64), 256, 0, stream>>>(qb, kb, vtb, eb, zb);
    outproj_mfma<<<(NB * S_LEN / 128) * (EMB / 64), 256, 0, stream>>>(zb, wob, bo, out);
}